// Round 6
// baseline (385.487 us; speedup 1.0000x reference)
//
#include <hip/hip_runtime.h>
#include <hip/hip_bf16.h>
#include <stdint.h>

#define N_ENC 2048
#define BATCH 32
#define M_TOT (N_ENC * BATCH)   // 65536 rows (s*32+b)
#define K_DIM 1024
#define N_DIM 1024
#define BM 256
#define BN 256
#define BK 64
#define NT (K_DIM / BK)          // 16 K-tiles

typedef __attribute__((ext_vector_type(4))) float f32x4;
typedef __attribute__((ext_vector_type(8))) short short8;

__device__ __forceinline__ unsigned int pack_bf16x2(float lo, float hi) {
  unsigned int a = __float_as_uint(lo);
  unsigned int b = __float_as_uint(hi);
  a = (a + 0x7fffu + ((a >> 16) & 1u)) >> 16;          // RNE to bf16, low half
  b = (b + 0x7fffu + ((b >> 16) & 1u)) & 0xffff0000u;  // RNE to bf16, high half
  return a | b;
}

__device__ __forceinline__ float bf2f(unsigned short u) {
  return __uint_as_float((unsigned int)u << 16);
}

__device__ __forceinline__ float tanh_fast(float x) {
  float e = __expf(2.0f * x);
  return 1.0f - 2.0f / (e + 1.0f);
}

// ---- f32 -> bf16 bulk convert, grid-stride ----
__global__ void k_convert_bf16(const float* __restrict__ src,
                               unsigned short* __restrict__ dst, int n8) {
  for (int i = blockIdx.x * 256 + threadIdx.x; i < n8; i += gridDim.x * 256) {
    const float* p = src + (size_t)i * 8;
    f32x4 v0 = *(const f32x4*)p;
    f32x4 v1 = *(const f32x4*)(p + 4);
    uint4 o;
    o.x = pack_bf16x2(v0.x, v0.y);
    o.y = pack_bf16x2(v0.z, v0.w);
    o.z = pack_bf16x2(v1.x, v1.y);
    o.w = pack_bf16x2(v1.z, v1.w);
    *(uint4*)(dst + (size_t)i * 8) = o;
  }
}

// ---- proj_dec[b][h] = sum_d dec[b][d] * w_dec[h][d] ----
__global__ void k_proj_dec(const float* __restrict__ dec,
                           const float* __restrict__ w_dec,
                           float* __restrict__ proj) {
  int t = threadIdx.x;
  int hh = t & 7, b = t >> 3;
  int h = blockIdx.x * 8 + hh;
  const float* wr = w_dec + (size_t)h * K_DIM;
  const float* dr = dec + (size_t)b * K_DIM;
  float acc = 0.f;
  for (int d = 0; d < K_DIM; d += 4) {
    f32x4 wv = *(const f32x4*)(wr + d);
    f32x4 dv = *(const f32x4*)(dr + d);
    acc = fmaf(wv.x, dv.x, acc);
    acc = fmaf(wv.y, dv.y, acc);
    acc = fmaf(wv.z, dv.z, acc);
    acc = fmaf(wv.w, dv.w, acc);
  }
  proj[b * N_DIM + h] = acc;
}

// ---- persistent 256x256-tile fused GEMM, 8 waves, rolling counted-vmcnt ----
// grid = 256 blocks; block b owns A-panel mt=b (rows b*256..b*256+255) and
// loops nt = 0..3. The stage cadence rolls across output tiles: pipeline
// never drains (tiles 13-15 stage the next output-tile's T0/T1/B-T1).
__global__ __launch_bounds__(512, 2) void k_gemm256p(
    const unsigned short* __restrict__ Abf,  // enc bf16 [65536][1024]
    const unsigned short* __restrict__ B,    // w_enc bf16 [1024][1024]
    const float* __restrict__ pdec,          // [32][1024]
    const float* __restrict__ wout,          // [1024]
    float* __restrict__ logits)              // [65536] (pre-zeroed)
{
  __shared__ __align__(16) unsigned short Asm[2][BM * BK];  // 2 x 32 KiB
  __shared__ __align__(16) unsigned short Bsm[2][BN * BK];  // 2 x 32 KiB

  const int mt = blockIdx.x;               // 0..255
  const int m0 = mt * BM;
  const int t = threadIdx.x;
  const int lane = t & 63;
  const int w = t >> 6;                    // 0..7
  const int wm = w >> 2, wn = w & 3;       // 2M x 4N waves; per-wave 128x64
  const int g = lane >> 4, c16 = lane & 15;

  // per-thread global source pointers (pre-swizzled); rounds 0-3 = A, 4-7 = B
  const unsigned short* gsrc[8];
#pragma unroll
  for (int r = 0; r < 4; ++r) {
    int i = r * 512 + t;
    int row = i >> 3;
    int sub = (i & 7) ^ (row & 7);         // inverse swizzle on SOURCE
    gsrc[r]     = Abf + (size_t)(m0 + row) * K_DIM + sub * 8;
    gsrc[4 + r] = B   + (size_t)row * K_DIM + sub * 8;   // nt=0 quarter
  }

#define GLD(PTR, LDSP)                                                         \
  __builtin_amdgcn_global_load_lds(                                            \
      (const __attribute__((address_space(1))) void*)(PTR),                    \
      (__attribute__((address_space(3))) void*)(LDSP), 16, 0, 0)

  // stage A half-tile H (rounds 2H,2H+1) of some tile into buf BSEL; bump ptrs
#define STAGE_A2(H, BSEL, BUMP)                                                \
  {                                                                            \
    GLD(gsrc[(H)*2],     &Asm[BSEL][(((H)*2) * 512 + w * 64) * 8]);            \
    gsrc[(H)*2] += (BUMP);                                                     \
    GLD(gsrc[(H)*2 + 1], &Asm[BSEL][(((H)*2 + 1) * 512 + w * 64) * 8]);        \
    gsrc[(H)*2 + 1] += (BUMP);                                                 \
  }
#define STAGE_B2(H, BSEL, BUMP)                                                \
  {                                                                            \
    GLD(gsrc[4 + (H)*2],     &Bsm[BSEL][(((H)*2) * 512 + w * 64) * 8]);        \
    gsrc[4 + (H)*2] += (BUMP);                                                 \
    GLD(gsrc[4 + (H)*2 + 1], &Bsm[BSEL][(((H)*2 + 1) * 512 + w * 64) * 8]);    \
    gsrc[4 + (H)*2 + 1] += (BUMP);                                             \
  }

#define RD_A(MH, BSEL)                                                         \
  _Pragma("unroll")                                                            \
  for (int mf2 = 0; mf2 < 4; ++mf2)                                            \
    _Pragma("unroll")                                                          \
    for (int ks = 0; ks < 2; ++ks) {                                           \
      int row = wm * 128 + (MH)*64 + mf2 * 16 + c16;                           \
      int sub = ks * 4 + g;                                                    \
      afr[mf2 * 2 + ks] =                                                      \
          *(const short8*)&Asm[BSEL][row * 64 + ((sub ^ (row & 7)) * 8)];      \
    }
#define RD_B(dst, NH, BSEL)                                                    \
  _Pragma("unroll")                                                            \
  for (int nf2 = 0; nf2 < 2; ++nf2)                                            \
    _Pragma("unroll")                                                          \
    for (int ks = 0; ks < 2; ++ks) {                                           \
      int row = wn * 64 + (NH)*32 + nf2 * 16 + c16;                            \
      int sub = ks * 4 + g;                                                    \
      dst[nf2 * 2 + ks] =                                                      \
          *(const short8*)&Bsm[BSEL][row * 64 + ((sub ^ (row & 7)) * 8)];      \
    }
#define MMQ(MH, NH, BREG)                                                      \
  __builtin_amdgcn_s_setprio(1);                                               \
  _Pragma("unroll")                                                            \
  for (int mf2 = 0; mf2 < 4; ++mf2)                                            \
    _Pragma("unroll")                                                          \
    for (int nf2 = 0; nf2 < 2; ++nf2)                                          \
      _Pragma("unroll")                                                        \
      for (int ks = 0; ks < 2; ++ks)                                           \
        acc[(MH)*4 + mf2][(NH)*2 + nf2] =                                      \
            __builtin_amdgcn_mfma_f32_16x16x32_bf16(                           \
                afr[mf2 * 2 + ks], BREG[nf2 * 2 + ks],                         \
                acc[(MH)*4 + mf2][(NH)*2 + nf2], 0, 0, 0);                     \
  __builtin_amdgcn_s_setprio(0);

#define BAR() __builtin_amdgcn_s_barrier()

  // One K-tile: 4 phases. Stages: A of T_{m+1} (ph0,ph1 -> other buf),
  // B of T_{m+2} (ph2,ph3 -> current buf; its B-reads completed at ph1).
  // Per-wave counted vmcnt(4) + barrier at tile end = correctness protocol.
#define TILE(BSEL, ABUMP, BBUMP)                                               \
  {                                                                            \
    short8 afr[8], b0[4], b1[4];                                               \
    RD_A(0, BSEL);                                                             \
    RD_B(b0, 0, BSEL);                                                         \
    STAGE_A2(0, (BSEL) ^ 1, ABUMP);                                            \
    BAR();                                                                     \
    MMQ(0, 0, b0);                                                             \
    BAR();                                                                     \
    RD_B(b1, 1, BSEL);                                                         \
    STAGE_A2(1, (BSEL) ^ 1, ABUMP);                                            \
    BAR();                                                                     \
    MMQ(0, 1, b1);                                                             \
    BAR();                                                                     \
    RD_A(1, BSEL);                                                             \
    STAGE_B2(0, BSEL, BBUMP);                                                  \
    BAR();                                                                     \
    MMQ(1, 1, b1);                                                             \
    BAR();                                                                     \
    STAGE_B2(1, BSEL, BBUMP);                                                  \
    BAR();                                                                     \
    MMQ(1, 0, b0);                                                             \
    asm volatile("s_waitcnt vmcnt(4)" ::: "memory");                           \
    __builtin_amdgcn_sched_barrier(0);                                         \
    BAR();                                                                     \
  }

  // ---- prologue: T0 fully (buf0) + B of T1 (buf1); 12 loads ----
  STAGE_B2(0, 0, BK); STAGE_B2(1, 0, BK);      // B(T0)
  STAGE_A2(0, 0, BK); STAGE_A2(1, 0, BK);      // A(T0)
  STAGE_B2(0, 1, BK); STAGE_B2(1, 1, BK);      // B(T1)
  asm volatile("s_waitcnt vmcnt(4)" ::: "memory");  // T0 landed; B(T1) in flight
  __builtin_amdgcn_sched_barrier(0);
  BAR();

  for (int nt4 = 0; nt4 < 4; ++nt4) {
    const int n0 = nt4 * BN;
    // B rolling jump (in shorts), applied after the m=13 stage: advance to the
    // next nt quarter at k=0 (wrap to nt=0 after the last quarter).
    const int bj = (nt4 < 3) ? (255 * K_DIM + BK) : (-769 * K_DIM + BK);
    const int aw = BK - K_DIM;   // A wrap (same rows, k back to 0), at m=14

    f32x4 acc[8][4];
#pragma unroll
    for (int mf = 0; mf < 8; ++mf)
#pragma unroll
      for (int nf = 0; nf < 4; ++nf) acc[mf][nf] = {0.f, 0.f, 0.f, 0.f};

    // K-tiles 0..11 (unrolled x2: static buffer selectors)
    for (int it = 0; it < 6; ++it) {
      TILE(0, BK, BK);
      TILE(1, BK, BK);
    }
    TILE(0, BK, BK);   // m=12
    TILE(1, BK, bj);   // m=13: B stages jump to next output-tile's T0
    TILE(0, aw, BK);   // m=14: A stages wrap to k=0 (next tile's T0 rows)
    TILE(1, BK, BK);   // m=15: stages A(next T1... next T0) / B(next T1)

    // ---- epilogue: tanh(acc + pdec) . wout, shfl-reduce, atomicAdd ----
    // Runs while next output-tile's loads are in flight (no LDS use here).
#pragma unroll
    for (int pe = 0; pe < 2; ++pe) {
      // hoist the 16 pdec values used by this mf-parity half
      float pdv[4][4];
#pragma unroll
      for (int nf = 0; nf < 4; ++nf) {
#pragma unroll
        for (int j = 0; j < 4; ++j) {
          const int bidx = (pe * 16 + g * 4 + j) & 31;
          pdv[nf][j] = pdec[bidx * N_DIM + n0 + wn * 64 + nf * 16 + c16];
        }
      }
#pragma unroll
      for (int mh = 0; mh < 4; ++mh) {
        const int mf = mh * 2 + pe;
        float psum[4] = {0.f, 0.f, 0.f, 0.f};
#pragma unroll
        for (int nf = 0; nf < 4; ++nf) {
          const float wo = wout[n0 + wn * 64 + nf * 16 + c16];
#pragma unroll
          for (int j = 0; j < 4; ++j) {
            float v = acc[mf][nf][j] + pdv[nf][j];
            psum[j] = fmaf(tanh_fast(v), wo, psum[j]);
          }
        }
#pragma unroll
        for (int j = 0; j < 4; ++j) {
          float p = psum[j];
          p += __shfl_xor(p, 1);
          p += __shfl_xor(p, 2);
          p += __shfl_xor(p, 4);
          p += __shfl_xor(p, 8);
          if (c16 == 0)
            atomicAdd(&logits[m0 + wm * 128 + mf * 16 + g * 4 + j], p);
        }
      }
    }
  }
  // protect LDS against landing loads after block retires
  asm volatile("s_waitcnt vmcnt(0)" ::: "memory");

#undef TILE
#undef STAGE_A2
#undef STAGE_B2
#undef GLD
#undef RD_A
#undef RD_B
#undef MMQ
#undef BAR
}

// ---- fallback f32-A 128^2 GEMM (used only if ws too small for enc_bf) ----
__global__ __launch_bounds__(256) void k_gemm_f32(
    const float* __restrict__ A,
    const unsigned short* __restrict__ B,
    const float* __restrict__ pdec,
    const float* __restrict__ wout,
    float* __restrict__ logits)
{
  __shared__ __align__(16) unsigned short Asm[128 * BK];
  __shared__ __align__(16) unsigned short Bsm[128 * BK];
  const int bid = blockIdx.x;
  const int nt = bid & 7;
  const int mt = bid >> 3;
  const int m0 = mt * 128, n0 = nt * 128;
  const int t = threadIdx.x;
  const int lane = t & 63;
  const int w = t >> 6;
  const int wm = w >> 1, wn = w & 1;
  const int g = lane >> 4, c16 = lane & 15;

  f32x4 acc[4][4];
#pragma unroll
  for (int a = 0; a < 4; ++a)
#pragma unroll
    for (int b = 0; b < 4; ++b) acc[a][b] = {0.f, 0.f, 0.f, 0.f};

  for (int kt = 0; kt < NT; ++kt) {
    const int k0 = kt * BK;
#pragma unroll
    for (int i = 0; i < 4; ++i) {
      int item = i * 256 + t;
      int row = item >> 3;
      int sub = item & 7;
      const float* src = A + (size_t)(m0 + row) * K_DIM + k0 + sub * 8;
      f32x4 v0 = *(const f32x4*)src;
      f32x4 v1 = *(const f32x4*)(src + 4);
      uint4 o;
      o.x = pack_bf16x2(v0.x, v0.y);
      o.y = pack_bf16x2(v0.z, v0.w);
      o.z = pack_bf16x2(v1.x, v1.y);
      o.w = pack_bf16x2(v1.z, v1.w);
      int chunk = sub ^ (row & 7);
      *(uint4*)&Asm[row * 64 + chunk * 8] = o;
    }
#pragma unroll
    for (int j = 0; j < 4; ++j) {
      int chunkid = w * 4 + j;
      int item = chunkid * 64 + lane;
      int row = item >> 3;
      int sub = (item & 7) ^ (row & 7);
      const unsigned short* gp = B + (size_t)(n0 + row) * K_DIM + k0 + sub * 8;
      __builtin_amdgcn_global_load_lds(
          (const __attribute__((address_space(1))) void*)gp,
          (__attribute__((address_space(3))) void*)&Bsm[chunkid * 512],
          16, 0, 0);
    }
    __syncthreads();
#pragma unroll
    for (int ks = 0; ks < 2; ++ks) {
      const int sub = ks * 4 + g;
      short8 af[4], bfr[4];
#pragma unroll
      for (int a = 0; a < 4; ++a) {
        int row = wm * 64 + a * 16 + c16;
        af[a] = *(const short8*)&Asm[row * 64 + ((sub ^ (row & 7)) * 8)];
      }
#pragma unroll
      for (int b = 0; b < 4; ++b) {
        int row = wn * 64 + b * 16 + c16;
        bfr[b] = *(const short8*)&Bsm[row * 64 + ((sub ^ (row & 7)) * 8)];
      }
#pragma unroll
      for (int a = 0; a < 4; ++a)
#pragma unroll
        for (int b = 0; b < 4; ++b)
          acc[a][b] = __builtin_amdgcn_mfma_f32_16x16x32_bf16(
              af[a], bfr[b], acc[a][b], 0, 0, 0);
    }
    __syncthreads();
  }
#pragma unroll
  for (int a = 0; a < 4; ++a) {
    float psum[4] = {0.f, 0.f, 0.f, 0.f};
#pragma unroll
    for (int b = 0; b < 4; ++b) {
      const int col = n0 + wn * 64 + b * 16 + c16;
      const float wo = wout[col];
#pragma unroll
      for (int j = 0; j < 4; ++j) {
        const int rl = wm * 64 + a * 16 + g * 4 + j;
        const int bidx = rl & 31;
        float v = acc[a][b][j] + pdec[bidx * N_DIM + col];
        psum[j] = fmaf(tanh_fast(v), wo, psum[j]);
      }
    }
#pragma unroll
    for (int j = 0; j < 4; ++j) {
      float p = psum[j];
      p += __shfl_xor(p, 1);
      p += __shfl_xor(p, 2);
      p += __shfl_xor(p, 4);
      p += __shfl_xor(p, 8);
      if (c16 == 0)
        atomicAdd(&logits[m0 + wm * 64 + a * 16 + g * 4 + j], p);
    }
  }
}

// ---- masked softmax over s per batch column; mask dtype auto-detected ----
__global__ void k_softmax(const float* __restrict__ logits,
                          const void* __restrict__ maskp,
                          float* __restrict__ weights) {
  const int b = blockIdx.x;
  const int t = threadIdx.x;
  const int lane = t & 63, wid = t >> 6;
  __shared__ float red[8];
  __shared__ int modeflags[2];

  if (t < 2) modeflags[t] = 0;
  __syncthreads();
  unsigned int w0 = ((const unsigned int*)maskp)[t];
  if (w0 == 0x3f800000u) modeflags[1] = 1;
  else if (w0 > 1u) modeflags[0] = 1;
  __syncthreads();
  const int mode = modeflags[1] ? 2 : (modeflags[0] ? 1 : 0);

  float v[8];
  float mx = -3.0e38f;
#pragma unroll
  for (int i = 0; i < 8; ++i) {
    int idx = (t + i * 256) * BATCH + b;
    float l = logits[idx];
    int mk;
    if (mode == 0) mk = ((const int*)maskp)[idx];
    else if (mode == 1) mk = ((const unsigned char*)maskp)[idx];
    else mk = (((const float*)maskp)[idx] != 0.f);
    l = mk ? l : -2.0e9f;
    v[i] = l;
    mx = fmaxf(mx, l);
  }
#pragma unroll
  for (int off = 1; off < 64; off <<= 1) mx = fmaxf(mx, __shfl_xor(mx, off));
  if (lane == 0) red[wid] = mx;
  __syncthreads();
  mx = fmaxf(fmaxf(red[0], red[1]), fmaxf(red[2], red[3]));

  float sum = 0.f;
#pragma unroll
  for (int i = 0; i < 8; ++i) {
    float e = __expf(v[i] - mx);
    v[i] = e;
    sum += e;
  }
#pragma unroll
  for (int off = 1; off < 64; off <<= 1) sum += __shfl_xor(sum, off);
  if (lane == 0) red[4 + wid] = sum;
  __syncthreads();
  sum = red[4] + red[5] + red[6] + red[7];
  float inv = 1.0f / sum;
#pragma unroll
  for (int i = 0; i < 8; ++i)
    weights[(t + i * 256) * BATCH + b] = v[i] * inv;
}

// ---- attn_response[b][e] = sum_s w[s][b] * enc_bf[s][b][e] ----
__global__ void k_response_bf(const unsigned short* __restrict__ enc_bf,
                              const float* __restrict__ weights,
                              float* __restrict__ out) {
  const int b = blockIdx.x & 31;
  const int ch = blockIdx.x >> 5;
  const int e = threadIdx.x * 4;
  float a0 = 0.f, a1 = 0.f, a2 = 0.f, a3 = 0.f;
  const int s0 = ch * (N_ENC / 16);
  for (int s = s0; s < s0 + N_ENC / 16; ++s) {
    float wv = weights[s * BATCH + b];
    ushort4 x = *(const ushort4*)(enc_bf + ((size_t)s * BATCH + b) * K_DIM + e);
    a0 = fmaf(wv, bf2f(x.x), a0);
    a1 = fmaf(wv, bf2f(x.y), a1);
    a2 = fmaf(wv, bf2f(x.z), a2);
    a3 = fmaf(wv, bf2f(x.w), a3);
  }
  atomicAdd(&out[b * K_DIM + e + 0], a0);
  atomicAdd(&out[b * K_DIM + e + 1], a1);
  atomicAdd(&out[b * K_DIM + e + 2], a2);
  atomicAdd(&out[b * K_DIM + e + 3], a3);
}

__global__ void k_response(const float* __restrict__ enc,
                           const float* __restrict__ weights,
                           float* __restrict__ out) {
  const int b = blockIdx.x & 31;
  const int ch = blockIdx.x >> 5;
  const int e = threadIdx.x * 4;
  float a0 = 0.f, a1 = 0.f, a2 = 0.f, a3 = 0.f;
  const int s0 = ch * (N_ENC / 16);
  for (int s = s0; s < s0 + N_ENC / 16; ++s) {
    float wv = weights[s * BATCH + b];
    f32x4 x = *(const f32x4*)(enc + ((size_t)s * BATCH + b) * K_DIM + e);
    a0 = fmaf(wv, x.x, a0);
    a1 = fmaf(wv, x.y, a1);
    a2 = fmaf(wv, x.z, a2);
    a3 = fmaf(wv, x.w, a3);
  }
  atomicAdd(&out[b * K_DIM + e + 0], a0);
  atomicAdd(&out[b * K_DIM + e + 1], a1);
  atomicAdd(&out[b * K_DIM + e + 2], a2);
  atomicAdd(&out[b * K_DIM + e + 3], a3);
}

extern "C" void kernel_launch(void* const* d_in, const int* in_sizes, int n_in,
                              void* d_out, int out_size, void* d_ws, size_t ws_size,
                              hipStream_t stream) {
  const float* enc   = (const float*)d_in[0];
  const void*  mask  = d_in[1];
  const float* dec   = (const float*)d_in[2];
  const float* w_enc = (const float*)d_in[3];
  const float* w_dec = (const float*)d_in[4];
  const float* w_out = (const float*)d_in[5];

  float* out_resp = (float*)d_out;                 // [32*1024]
  float* out_w    = out_resp + BATCH * K_DIM;      // [2048*32]

  const size_t enc_bf_bytes = (size_t)M_TOT * K_DIM * 2;       // 128 MiB
  const size_t need = enc_bf_bytes + 2 * 1024 * 1024 + 128 * 1024 + 256 * 1024;
  const bool pre = ws_size >= need;

  char* wsB = (char*)d_ws;
  unsigned short* enc_bf   = (unsigned short*)wsB;
  size_t off = pre ? enc_bf_bytes : 0;
  unsigned short* w_enc_bf = (unsigned short*)(wsB + off);     off += 2 * 1024 * 1024;
  float* pdec   = (float*)(wsB + off);                         off += 128 * 1024;
  float* logits = (float*)(wsB + off);

  hipMemsetAsync(logits, 0, (size_t)M_TOT * sizeof(float), stream);
  hipMemsetAsync(out_resp, 0, (size_t)BATCH * K_DIM * sizeof(float), stream);

  k_convert_bf16<<<512, 256, 0, stream>>>(w_enc, w_enc_bf, N_DIM * K_DIM / 8);
  k_proj_dec<<<N_DIM / 8, 256, 0, stream>>>(dec, w_dec, pdec);

  if (pre) {
    k_convert_bf16<<<2048, 256, 0, stream>>>(enc, enc_bf, M_TOT * (K_DIM / 8));
    k_gemm256p<<<M_TOT / BM, 512, 0, stream>>>(
        enc_bf, w_enc_bf, pdec, w_out, logits);
  } else {
    k_gemm_f32<<<(M_TOT / 128) * (N_DIM / 128), 256, 0, stream>>>(
        enc, w_enc_bf, pdec, w_out, logits);
  }

  k_softmax<<<BATCH, 256, 0, stream>>>(logits, mask, out_w);

  if (pre) {
    k_response_bf<<<BATCH * 16, 256, 0, stream>>>(enc_bf, out_w, out_resp);
  } else {
    k_response<<<BATCH * 16, 256, 0, stream>>>(enc, out_w, out_resp);
  }
}

// Round 7
// 344.960 us; speedup vs baseline: 1.1175x; 1.1175x over previous
//
#include <hip/hip_runtime.h>
#include <hip/hip_bf16.h>
#include <stdint.h>

#define N_ENC 2048
#define BATCH 32
#define M_TOT (N_ENC * BATCH)   // 65536 rows (s*32+b)
#define K_DIM 1024
#define N_DIM 1024
#define BM 256
#define BN 256
#define BK 64
#define NT (K_DIM / BK)          // 16 K-tiles

typedef __attribute__((ext_vector_type(4))) float f32x4;
typedef __attribute__((ext_vector_type(8))) short short8;

__device__ __forceinline__ unsigned int pack_bf16x2(float lo, float hi) {
  unsigned int a = __float_as_uint(lo);
  unsigned int b = __float_as_uint(hi);
  a = (a + 0x7fffu + ((a >> 16) & 1u)) >> 16;          // RNE to bf16, low half
  b = (b + 0x7fffu + ((b >> 16) & 1u)) & 0xffff0000u;  // RNE to bf16, high half
  return a | b;
}

__device__ __forceinline__ float bf2f(unsigned short u) {
  return __uint_as_float((unsigned int)u << 16);
}

__device__ __forceinline__ float tanh_fast(float x) {
  float e = __expf(2.0f * x);
  return 1.0f - 2.0f / (e + 1.0f);
}

// ---- f32 -> bf16 bulk convert, grid-stride ----
__global__ void k_convert_bf16(const float* __restrict__ src,
                               unsigned short* __restrict__ dst, int n8) {
  for (int i = blockIdx.x * 256 + threadIdx.x; i < n8; i += gridDim.x * 256) {
    const float* p = src + (size_t)i * 8;
    f32x4 v0 = *(const f32x4*)p;
    f32x4 v1 = *(const f32x4*)(p + 4);
    uint4 o;
    o.x = pack_bf16x2(v0.x, v0.y);
    o.y = pack_bf16x2(v0.z, v0.w);
    o.z = pack_bf16x2(v1.x, v1.y);
    o.w = pack_bf16x2(v1.z, v1.w);
    *(uint4*)(dst + (size_t)i * 8) = o;
  }
}

// ---- proj_dec[b][h] = sum_d dec[b][d] * w_dec[h][d] ----
__global__ void k_proj_dec(const float* __restrict__ dec,
                           const float* __restrict__ w_dec,
                           float* __restrict__ proj) {
  int t = threadIdx.x;
  int hh = t & 7, b = t >> 3;
  int h = blockIdx.x * 8 + hh;
  const float* wr = w_dec + (size_t)h * K_DIM;
  const float* dr = dec + (size_t)b * K_DIM;
  float acc = 0.f;
  for (int d = 0; d < K_DIM; d += 4) {
    f32x4 wv = *(const f32x4*)(wr + d);
    f32x4 dv = *(const f32x4*)(dr + d);
    acc = fmaf(wv.x, dv.x, acc);
    acc = fmaf(wv.y, dv.y, acc);
    acc = fmaf(wv.z, dv.z, acc);
    acc = fmaf(wv.w, dv.w, acc);
  }
  proj[b * N_DIM + h] = acc;
}

// ---- 256x256-tile fused GEMM, 8 waves, 8-phase counted-vmcnt schedule ----
// Identical sync protocol to round 5 (verified): per-tile counted vmcnt(4),
// stage-after-drain invariant held by asm waitcnt + s_barrier ordering.
// Changes vs round 5: NO sched_barrier(0) anywhere (m141: order-pinning
// defeats compiler scheduling); K-loop unrolled x2 for static bsel.
__global__ __launch_bounds__(512, 2) void k_gemm256(
    const unsigned short* __restrict__ Abf,  // enc bf16 [65536][1024]
    const unsigned short* __restrict__ B,    // w_enc bf16 [1024][1024]
    const float* __restrict__ pdec,          // [32][1024]
    const float* __restrict__ wout,          // [1024]
    float* __restrict__ logits)              // [65536] (pre-zeroed)
{
  __shared__ __align__(16) unsigned short Asm[2][BM * BK];  // 2 x 32 KiB
  __shared__ __align__(16) unsigned short Bsm[2][BN * BK];  // 2 x 32 KiB

  // XCD-aware bijective swizzle: 4 n-siblings of one A-tile -> same XCD.
  const int nwg = (M_TOT / BM) * (N_DIM / BN);   // 1024, %8==0
  const int cpx = nwg / 8;                       // 128
  const int bid = ((int)blockIdx.x % 8) * cpx + (int)blockIdx.x / 8;
  const int nt4 = bid & 3;       // n fastest: 4 siblings share an A tile
  const int mt = bid >> 2;
  const int m0 = mt * BM, n0 = nt4 * BN;
  const int t = threadIdx.x;
  const int lane = t & 63;
  const int w = t >> 6;                   // 0..7
  const int wm = w >> 2, wn = w & 3;      // 2M x 4N waves; per-wave 128x64
  const int g = lane >> 4, c16 = lane & 15;

  const f32x4 zero = {0.f, 0.f, 0.f, 0.f};
  f32x4 acc[8][4];
#pragma unroll
  for (int mf = 0; mf < 8; ++mf)
#pragma unroll
    for (int nf = 0; nf < 4; ++nf) acc[mf][nf] = zero;

  // per-thread global source pointers (pre-swizzled), bump += BK per staged tile
  const unsigned short* gsrc[8];
#pragma unroll
  for (int r = 0; r < 4; ++r) {
    int i = r * 512 + t;
    int row = i >> 3;
    int sub = (i & 7) ^ (row & 7);         // inverse swizzle on SOURCE
    gsrc[r]     = Abf + (size_t)(m0 + row) * K_DIM + sub * 8;
    gsrc[4 + r] = B   + (size_t)(n0 + row) * K_DIM + sub * 8;
  }

#define STAGE_A(H, BSEL)                                                       \
  {                                                                            \
    const int r0 = (H) * 2;                                                    \
    __builtin_amdgcn_global_load_lds(                                          \
        (const __attribute__((address_space(1))) void*)gsrc[r0],               \
        (__attribute__((address_space(3))) void*)                              \
            &Asm[BSEL][(r0 * 512 + w * 64) * 8], 16, 0, 0);                    \
    gsrc[r0] += BK;                                                            \
    __builtin_amdgcn_global_load_lds(                                          \
        (const __attribute__((address_space(1))) void*)gsrc[r0 + 1],           \
        (__attribute__((address_space(3))) void*)                              \
            &Asm[BSEL][((r0 + 1) * 512 + w * 64) * 8], 16, 0, 0);              \
    gsrc[r0 + 1] += BK;                                                        \
  }
#define STAGE_B(H, BSEL)                                                       \
  {                                                                            \
    const int r0 = (H) * 2;                                                    \
    __builtin_amdgcn_global_load_lds(                                          \
        (const __attribute__((address_space(1))) void*)gsrc[4 + r0],           \
        (__attribute__((address_space(3))) void*)                              \
            &Bsm[BSEL][(r0 * 512 + w * 64) * 8], 16, 0, 0);                    \
    gsrc[4 + r0] += BK;                                                        \
    __builtin_amdgcn_global_load_lds(                                          \
        (const __attribute__((address_space(1))) void*)gsrc[4 + r0 + 1],       \
        (__attribute__((address_space(3))) void*)                              \
            &Bsm[BSEL][((r0 + 1) * 512 + w * 64) * 8], 16, 0, 0);              \
    gsrc[4 + r0 + 1] += BK;                                                    \
  }

#define RD_A(MH, BSEL)                                                         \
  _Pragma("unroll")                                                            \
  for (int mf2 = 0; mf2 < 4; ++mf2)                                            \
    _Pragma("unroll")                                                          \
    for (int ks = 0; ks < 2; ++ks) {                                           \
      int row = wm * 128 + (MH)*64 + mf2 * 16 + c16;                           \
      int sub = ks * 4 + g;                                                    \
      afr[mf2 * 2 + ks] =                                                      \
          *(const short8*)&Asm[BSEL][row * 64 + ((sub ^ (row & 7)) * 8)];      \
    }
#define RD_B(dst, NH, BSEL)                                                    \
  _Pragma("unroll")                                                            \
  for (int nf2 = 0; nf2 < 2; ++nf2)                                            \
    _Pragma("unroll")                                                          \
    for (int ks = 0; ks < 2; ++ks) {                                           \
      int row = wn * 64 + (NH)*32 + nf2 * 16 + c16;                            \
      int sub = ks * 4 + g;                                                    \
      dst[nf2 * 2 + ks] =                                                      \
          *(const short8*)&Bsm[BSEL][row * 64 + ((sub ^ (row & 7)) * 8)];      \
    }
#define MMQ(MH, NH, BREG)                                                      \
  __builtin_amdgcn_s_setprio(1);                                               \
  _Pragma("unroll")                                                            \
  for (int mf2 = 0; mf2 < 4; ++mf2)                                            \
    _Pragma("unroll")                                                          \
    for (int nf2 = 0; nf2 < 2; ++nf2)                                          \
      _Pragma("unroll")                                                        \
      for (int ks = 0; ks < 2; ++ks)                                           \
        acc[(MH)*4 + mf2][(NH)*2 + nf2] =                                      \
            __builtin_amdgcn_mfma_f32_16x16x32_bf16(                           \
                afr[mf2 * 2 + ks], BREG[nf2 * 2 + ks],                         \
                acc[(MH)*4 + mf2][(NH)*2 + nf2], 0, 0, 0);                     \
  __builtin_amdgcn_s_setprio(0);

#define BARRIER() __builtin_amdgcn_s_barrier()
  // lgkmcnt(0) BEFORE the phase-end barrier region: invariant "stage into a
  // region only after a barrier behind which all waves drained reads of it".
#define LGK0() asm volatile("s_waitcnt lgkmcnt(0)" ::: "memory")

  // ---- prologue: T0 fully (buf0) + B halves of T1 (buf1); 12 loads ----
  STAGE_B(0, 0); STAGE_B(1, 0); STAGE_A(0, 0); STAGE_A(1, 0);
  STAGE_B(0, 1); STAGE_B(1, 1);
  asm volatile("s_waitcnt vmcnt(4)" ::: "memory");  // T0 landed; T1 B in flight
  BARRIER();

#pragma unroll 2
  for (int m = 0; m < NT; ++m) {
    const int bsel = m & 1;
    const int nxt = bsel ^ 1;
    short8 afr[8], b0[4], b1[4];
    // -- phase 0: quadrant (0,0); stage A0 of T_{m+1} --
    RD_A(0, bsel);
    RD_B(b0, 0, bsel);
    if (m + 1 < NT) STAGE_A(0, nxt);
    BARRIER();
    LGK0();
    MMQ(0, 0, b0);
    BARRIER();
    // -- phase 1: quadrant (0,1); stage A1 of T_{m+1} --
    RD_B(b1, 1, bsel);
    if (m + 1 < NT) STAGE_A(1, nxt);
    BARRIER();
    LGK0();
    MMQ(0, 1, b1);
    BARRIER();
    // -- phase 2: quadrant (1,1); stage B0 of T_{m+2} (curr buf, B reads done) --
    RD_A(1, bsel);
    if (m + 2 < NT) STAGE_B(0, bsel);
    BARRIER();
    LGK0();
    MMQ(1, 1, b1);
    BARRIER();
    // -- phase 3: quadrant (1,0); stage B1 of T_{m+2}; end-of-tile vmcnt --
    if (m + 2 < NT) STAGE_B(1, bsel);
    BARRIER();
    MMQ(1, 0, b0);
    if (m == NT - 2) {
      asm volatile("s_waitcnt vmcnt(0)" ::: "memory");   // drain: T_{NT-1} landed
    } else if (m < NT - 2) {
      asm volatile("s_waitcnt vmcnt(4)" ::: "memory");   // T_{m+1} landed
    }
    BARRIER();
  }

#undef STAGE_A
#undef STAGE_B
#undef RD_A
#undef RD_B
#undef MMQ
#undef BARRIER
#undef LGK0

  // -- epilogue: tanh(acc + pdec) . wout, shfl-reduce 16 cols, atomic per row --
#pragma unroll
  for (int mf = 0; mf < 8; ++mf) {
    float psum[4] = {0.f, 0.f, 0.f, 0.f};
#pragma unroll
    for (int nf = 0; nf < 4; ++nf) {
      const int col = n0 + wn * 64 + nf * 16 + c16;
      const float wo = wout[col];
#pragma unroll
      for (int j = 0; j < 4; ++j) {
        const int rl = wm * 128 + mf * 16 + g * 4 + j;  // C/D: col=lane&15, row=(lane>>4)*4+j
        const int bidx = rl & 31;                       // m0 multiple of 32
        float v = acc[mf][nf][j] + pdec[bidx * N_DIM + col];
        psum[j] = fmaf(tanh_fast(v), wo, psum[j]);
      }
    }
#pragma unroll
    for (int j = 0; j < 4; ++j) {
      float p = psum[j];
      p += __shfl_xor(p, 1);
      p += __shfl_xor(p, 2);
      p += __shfl_xor(p, 4);
      p += __shfl_xor(p, 8);
      if (c16 == 0)
        atomicAdd(&logits[m0 + wm * 128 + mf * 16 + g * 4 + j], p);
    }
  }
}

// ---- fallback f32-A 128^2 GEMM (used only if ws too small for enc_bf) ----
__global__ __launch_bounds__(256) void k_gemm_f32(
    const float* __restrict__ A,
    const unsigned short* __restrict__ B,
    const float* __restrict__ pdec,
    const float* __restrict__ wout,
    float* __restrict__ logits)
{
  __shared__ __align__(16) unsigned short Asm[128 * BK];
  __shared__ __align__(16) unsigned short Bsm[128 * BK];
  const int bid = blockIdx.x;
  const int nt = bid & 7;
  const int mt = bid >> 3;
  const int m0 = mt * 128, n0 = nt * 128;
  const int t = threadIdx.x;
  const int lane = t & 63;
  const int w = t >> 6;
  const int wm = w >> 1, wn = w & 1;
  const int g = lane >> 4, c16 = lane & 15;

  f32x4 acc[4][4];
#pragma unroll
  for (int a = 0; a < 4; ++a)
#pragma unroll
    for (int b = 0; b < 4; ++b) acc[a][b] = {0.f, 0.f, 0.f, 0.f};

  for (int kt = 0; kt < NT; ++kt) {
    const int k0 = kt * BK;
#pragma unroll
    for (int i = 0; i < 4; ++i) {
      int item = i * 256 + t;
      int row = item >> 3;
      int sub = item & 7;
      const float* src = A + (size_t)(m0 + row) * K_DIM + k0 + sub * 8;
      f32x4 v0 = *(const f32x4*)src;
      f32x4 v1 = *(const f32x4*)(src + 4);
      uint4 o;
      o.x = pack_bf16x2(v0.x, v0.y);
      o.y = pack_bf16x2(v0.z, v0.w);
      o.z = pack_bf16x2(v1.x, v1.y);
      o.w = pack_bf16x2(v1.z, v1.w);
      int chunk = sub ^ (row & 7);
      *(uint4*)&Asm[row * 64 + chunk * 8] = o;
    }
#pragma unroll
    for (int j = 0; j < 4; ++j) {
      int chunkid = w * 4 + j;
      int item = chunkid * 64 + lane;
      int row = item >> 3;
      int sub = (item & 7) ^ (row & 7);
      const unsigned short* gp = B + (size_t)(n0 + row) * K_DIM + k0 + sub * 8;
      __builtin_amdgcn_global_load_lds(
          (const __attribute__((address_space(1))) void*)gp,
          (__attribute__((address_space(3))) void*)&Bsm[chunkid * 512],
          16, 0, 0);
    }
    __syncthreads();
#pragma unroll
    for (int ks = 0; ks < 2; ++ks) {
      const int sub = ks * 4 + g;
      short8 af[4], bfr[4];
#pragma unroll
      for (int a = 0; a < 4; ++a) {
        int row = wm * 64 + a * 16 + c16;
        af[a] = *(const short8*)&Asm[row * 64 + ((sub ^ (row & 7)) * 8)];
      }
#pragma unroll
      for (int b = 0; b < 4; ++b) {
        int row = wn * 64 + b * 16 + c16;
        bfr[b] = *(const short8*)&Bsm[row * 64 + ((sub ^ (row & 7)) * 8)];
      }
#pragma unroll
      for (int a = 0; a < 4; ++a)
#pragma unroll
        for (int b = 0; b < 4; ++b)
          acc[a][b] = __builtin_amdgcn_mfma_f32_16x16x32_bf16(
              af[a], bfr[b], acc[a][b], 0, 0, 0);
    }
    __syncthreads();
  }
#pragma unroll
  for (int a = 0; a < 4; ++a) {
    float psum[4] = {0.f, 0.f, 0.f, 0.f};
#pragma unroll
    for (int b = 0; b < 4; ++b) {
      const int col = n0 + wn * 64 + b * 16 + c16;
      const float wo = wout[col];
#pragma unroll
      for (int j = 0; j < 4; ++j) {
        const int rl = wm * 64 + a * 16 + g * 4 + j;
        const int bidx = rl & 31;
        float v = acc[a][b][j] + pdec[bidx * N_DIM + col];
        psum[j] = fmaf(tanh_fast(v), wo, psum[j]);
      }
    }
#pragma unroll
    for (int j = 0; j < 4; ++j) {
      float p = psum[j];
      p += __shfl_xor(p, 1);
      p += __shfl_xor(p, 2);
      p += __shfl_xor(p, 4);
      p += __shfl_xor(p, 8);
      if (c16 == 0)
        atomicAdd(&logits[m0 + wm * 64 + a * 16 + g * 4 + j], p);
    }
  }
}

// ---- masked softmax over s per batch column; mask dtype auto-detected ----
__global__ void k_softmax(const float* __restrict__ logits,
                          const void* __restrict__ maskp,
                          float* __restrict__ weights) {
  const int b = blockIdx.x;
  const int t = threadIdx.x;
  const int lane = t & 63, wid = t >> 6;
  __shared__ float red[8];
  __shared__ int modeflags[2];

  if (t < 2) modeflags[t] = 0;
  __syncthreads();
  unsigned int w0 = ((const unsigned int*)maskp)[t];
  if (w0 == 0x3f800000u) modeflags[1] = 1;
  else if (w0 > 1u) modeflags[0] = 1;
  __syncthreads();
  const int mode = modeflags[1] ? 2 : (modeflags[0] ? 1 : 0);

  float v[8];
  float mx = -3.0e38f;
#pragma unroll
  for (int i = 0; i < 8; ++i) {
    int idx = (t + i * 256) * BATCH + b;
    float l = logits[idx];
    int mk;
    if (mode == 0) mk = ((const int*)maskp)[idx];
    else if (mode == 1) mk = ((const unsigned char*)maskp)[idx];
    else mk = (((const float*)maskp)[idx] != 0.f);
    l = mk ? l : -2.0e9f;
    v[i] = l;
    mx = fmaxf(mx, l);
  }
#pragma unroll
  for (int off = 1; off < 64; off <<= 1) mx = fmaxf(mx, __shfl_xor(mx, off));
  if (lane == 0) red[wid] = mx;
  __syncthreads();
  mx = fmaxf(fmaxf(red[0], red[1]), fmaxf(red[2], red[3]));

  float sum = 0.f;
#pragma unroll
  for (int i = 0; i < 8; ++i) {
    float e = __expf(v[i] - mx);
    v[i] = e;
    sum += e;
  }
#pragma unroll
  for (int off = 1; off < 64; off <<= 1) sum += __shfl_xor(sum, off);
  if (lane == 0) red[4 + wid] = sum;
  __syncthreads();
  sum = red[4] + red[5] + red[6] + red[7];
  float inv = 1.0f / sum;
#pragma unroll
  for (int i = 0; i < 8; ++i)
    weights[(t + i * 256) * BATCH + b] = v[i] * inv;
}

// ---- attn_response[b][e] = sum_s w[s][b] * enc_bf[s][b][e] ----
__global__ void k_response_bf(const unsigned short* __restrict__ enc_bf,
                              const float* __restrict__ weights,
                              float* __restrict__ out) {
  const int b = blockIdx.x & 31;
  const int ch = blockIdx.x >> 5;
  const int e = threadIdx.x * 4;
  float a0 = 0.f, a1 = 0.f, a2 = 0.f, a3 = 0.f;
  const int s0 = ch * (N_ENC / 16);
  for (int s = s0; s < s0 + N_ENC / 16; ++s) {
    float wv = weights[s * BATCH + b];
    ushort4 x = *(const ushort4*)(enc_bf + ((size_t)s * BATCH + b) * K_DIM + e);
    a0 = fmaf(wv, bf2f(x.x), a0);
    a1 = fmaf(wv, bf2f(x.y), a1);
    a2 = fmaf(wv, bf2f(x.z), a2);
    a3 = fmaf(wv, bf2f(x.w), a3);
  }
  atomicAdd(&out[b * K_DIM + e + 0], a0);
  atomicAdd(&out[b * K_DIM + e + 1], a1);
  atomicAdd(&out[b * K_DIM + e + 2], a2);
  atomicAdd(&out[b * K_DIM + e + 3], a3);
}

__global__ void k_response(const float* __restrict__ enc,
                           const float* __restrict__ weights,
                           float* __restrict__ out) {
  const int b = blockIdx.x & 31;
  const int ch = blockIdx.x >> 5;
  const int e = threadIdx.x * 4;
  float a0 = 0.f, a1 = 0.f, a2 = 0.f, a3 = 0.f;
  const int s0 = ch * (N_ENC / 16);
  for (int s = s0; s < s0 + N_ENC / 16; ++s) {
    float wv = weights[s * BATCH + b];
    f32x4 x = *(const f32x4*)(enc + ((size_t)s * BATCH + b) * K_DIM + e);
    a0 = fmaf(wv, x.x, a0);
    a1 = fmaf(wv, x.y, a1);
    a2 = fmaf(wv, x.z, a2);
    a3 = fmaf(wv, x.w, a3);
  }
  atomicAdd(&out[b * K_DIM + e + 0], a0);
  atomicAdd(&out[b * K_DIM + e + 1], a1);
  atomicAdd(&out[b * K_DIM + e + 2], a2);
  atomicAdd(&out[b * K_DIM + e + 3], a3);
}

extern "C" void kernel_launch(void* const* d_in, const int* in_sizes, int n_in,
                              void* d_out, int out_size, void* d_ws, size_t ws_size,
                              hipStream_t stream) {
  const float* enc   = (const float*)d_in[0];
  const void*  mask  = d_in[1];
  const float* dec   = (const float*)d_in[2];
  const float* w_enc = (const float*)d_in[3];
  const float* w_dec = (const float*)d_in[4];
  const float* w_out = (const float*)d_in[5];

  float* out_resp = (float*)d_out;                 // [32*1024]
  float* out_w    = out_resp + BATCH * K_DIM;      // [2048*32]

  const size_t enc_bf_bytes = (size_t)M_TOT * K_DIM * 2;       // 128 MiB
  const size_t need = enc_bf_bytes + 2 * 1024 * 1024 + 128 * 1024 + 256 * 1024;
  const bool pre = ws_size >= need;

  char* wsB = (char*)d_ws;
  unsigned short* enc_bf   = (unsigned short*)wsB;
  size_t off = pre ? enc_bf_bytes : 0;
  unsigned short* w_enc_bf = (unsigned short*)(wsB + off);     off += 2 * 1024 * 1024;
  float* pdec   = (float*)(wsB + off);                         off += 128 * 1024;
  float* logits = (float*)(wsB + off);

  hipMemsetAsync(logits, 0, (size_t)M_TOT * sizeof(float), stream);
  hipMemsetAsync(out_resp, 0, (size_t)BATCH * K_DIM * sizeof(float), stream);

  k_convert_bf16<<<512, 256, 0, stream>>>(w_enc, w_enc_bf, N_DIM * K_DIM / 8);
  k_proj_dec<<<N_DIM / 8, 256, 0, stream>>>(dec, w_dec, pdec);

  if (pre) {
    k_convert_bf16<<<2048, 256, 0, stream>>>(enc, enc_bf, M_TOT * (K_DIM / 8));
    k_gemm256<<<(M_TOT / BM) * (N_DIM / BN), 512, 0, stream>>>(
        enc_bf, w_enc_bf, pdec, w_out, logits);
  } else {
    k_gemm_f32<<<(M_TOT / 128) * (N_DIM / 128), 256, 0, stream>>>(
        enc, w_enc_bf, pdec, w_out, logits);
  }

  k_softmax<<<BATCH, 256, 0, stream>>>(logits, mask, out_w);

  if (pre) {
    k_response_bf<<<BATCH * 16, 256, 0, stream>>>(enc_bf, out_w, out_resp);
  } else {
    k_response<<<BATCH * 16, 256, 0, stream>>>(enc, out_w, out_resp);
  }
}